// Round 1
// baseline (599.217 us; speedup 1.0000x reference)
//
#include <hip/hip_runtime.h>

// 2-layer GRU (reset_after, sigmoid gates, linear act, no bias) + Wout.
// B=16384, T=25, D=128. 256 blocks x 1024 threads (16 waves); block owns 64
// batch rows. Waves 0-7 = layer1 @ step it, waves 8-15 = layer2 @ step it-1.
// FLIPPED MFMA operands: weights = A operand (24 frags = 96 VGPRs), data = B
// operand streamed k-by-k from LDS. amdgpu_waves_per_eu(4,4) pins the
// register budget at 128/wave so the allocator cannot undershoot and spill
// the weights.
//
// ROUND 1 change: x is no longer staged through LDS at all. Previous version
// DMA'd x f32 into a 67.6 KB double-buffered LDS tile and every layer-1 wave
// re-read the full 32 KB tile per timestep (256 KB/iter of LDS reads, ~35%
// of LDS traffic, 8x redundant) and the global_load_lds queue forced a
// vmcnt(0) drain at every barrier. Now layer-1 waves load x directly
// global -> f32x4 registers -> pkrtz -> MFMA B operand. The 32 KB/step tile
// is L1/L2 resident (per-XCD working set ~1 MB of 4 MiB L2), so HBM traffic
// is unchanged; LDS drops to 69.6 KB (H1+H2 only) and x loads become
// compiler-pipelined VMEM that can overlap MFMA instead of serializing at
// the barrier.
// C/D = [d-col][batch]: h_prev re-read is 1 ds_read_b64, h write 1 b64.

typedef _Float16 half8 __attribute__((ext_vector_type(8)));
typedef __fp16  fp16x2 __attribute__((ext_vector_type(2)));
typedef __fp16  fp16x4 __attribute__((ext_vector_type(4)));
typedef float    f32x4 __attribute__((ext_vector_type(4)));

#define MFMA(a, b, c) __builtin_amdgcn_mfma_f32_16x16x32_f16((a), (b), (c), 0, 0, 0)

constexpr int T_STEPS = 25;
constexpr int D = 128;
constexpr int NG = 384;   // 3*D
constexpr int BT = 64;    // batch rows per block
constexpr int SH = 136;   // f16 row stride: 272 B == 16 mod 128 -> benign 2-way on b128

__device__ __forceinline__ float sigm(float v) {
    return __builtin_amdgcn_rcpf(1.0f + __expf(-v));
}

__device__ __forceinline__ half8 pkrtz8(const f32x4 v0, const f32x4 v1) {
    union { fp16x2 h2[4]; half8 h8; } u;
    u.h2[0] = __builtin_amdgcn_cvt_pkrtz(v0.x, v0.y);
    u.h2[1] = __builtin_amdgcn_cvt_pkrtz(v0.z, v0.w);
    u.h2[2] = __builtin_amdgcn_cvt_pkrtz(v1.x, v1.y);
    u.h2[3] = __builtin_amdgcn_cvt_pkrtz(v1.z, v1.w);
    return u.h8;
}

__global__ __attribute__((amdgpu_flat_work_group_size(1024, 1024),
                          amdgpu_waves_per_eu(4, 4)))
void gru2_kernel(
    const float* __restrict__ x, const float* __restrict__ W1,
    const float* __restrict__ U1, const float* __restrict__ W2,
    const float* __restrict__ U2, const float* __restrict__ Wout,
    float* __restrict__ out) {
    __shared__ _Float16 H1[2][BT * SH];  // h1 state, double-buffered (34.8 KB)
    __shared__ _Float16 H2[2][BT * SH];  // h2 state, double-buffered (34.8 KB)

    const int tid = threadIdx.x;
    const int w = tid >> 6, lane = tid & 63, l15 = lane & 15, quad = lane >> 4;
    const int layer = w >> 3;       // 0: layer1 waves, 1: layer2 waves
    const int d0 = (w & 7) * 16;    // this wave's 16-col d-slice per gate
    const int b0 = blockIdx.x * BT;

    // ---- one-time: this wave's [W;U] fragments as MFMA *A* operand ----
    // A-frag (16x16x32): lane holds A[m = l15][k = quad*8 + e]; element =
    // Wgt[k][gate*128 + d0 + l15]. k-tiles 0..3 = W rows, 4..7 = U rows.
    half8 wg[3][8];
    {
        const float* Wp = layer ? W2 : W1;
        const float* Up = layer ? U2 : U1;
#pragma unroll
        for (int g = 0; g < 3; ++g) {
            const int c = g * 128 + d0 + l15;
#pragma unroll
            for (int kt = 0; kt < 8; ++kt) {
                const float* src = (kt < 4 ? Wp : Up) + (size_t)((kt & 3) * 32 + quad * 8) * NG + c;
                half8 f;
#pragma unroll
                for (int e = 0; e < 8; ++e) f[e] = (_Float16)src[(size_t)e * NG];
                wg[g][kt] = f;
            }
        }
    }

    // zero initial states: L1 reads H1[0] at iter 0; L2 reads H2[1] at iter 1
    for (int idx = tid; idx < BT * SH; idx += 1024) {
        H1[0][idx] = (_Float16)0.f;
        H2[1][idx] = (_Float16)0.f;
    }
    __syncthreads();

#pragma unroll 1
    for (int it = 0; it <= T_STEPS; ++it) {
        const int p = it & 1, q = p ^ 1;
        const bool active = layer ? (it >= 1) : (it < T_STEPS);
        if (active) {
            const _Float16* Hst = layer ? H2[p] : H1[p];  // own state (h_prev)
            _Float16* Hout      = layer ? H2[q] : H1[q];  // own state dest
            const _Float16* Hin = H1[p];                  // layer-2 input = h1
#pragma unroll
            for (int nt = 0; nt < 4; ++nt) {
                const int bb = nt * 16 + l15;             // batch row (B-frag n)
                f32x4 cz = {0.f, 0.f, 0.f, 0.f}, cr = {0.f, 0.f, 0.f, 0.f};
                f32x4 cxh = {0.f, 0.f, 0.f, 0.f}, cuh = {0.f, 0.f, 0.f, 0.f};
                if (!layer) {
                    // x_t direct from global (L1/L2-hit after first wave):
                    // lane reads rows b0+bb, cols quad*8 + kt*32 .. +7
                    const float* bx = x + ((size_t)(b0 + bb) * T_STEPS + it) * D + quad * 8;
#pragma unroll
                    for (int kt = 0; kt < 4; ++kt) {  // input part (W): x_t f32
                        const f32x4 v0 = *(const f32x4*)(bx + kt * 32);
                        const f32x4 v1 = *(const f32x4*)(bx + kt * 32 + 4);
                        const half8 B = pkrtz8(v0, v1);
                        cz  = MFMA(wg[0][kt], B, cz);
                        cr  = MFMA(wg[1][kt], B, cr);
                        cxh = MFMA(wg[2][kt], B, cxh);
                    }
                } else {
                    const _Float16* bi = Hin + bb * SH + quad * 8;
#pragma unroll
                    for (int kt = 0; kt < 4; ++kt) {  // input part (W): h1 f16
                        const half8 B = *(const half8*)(bi + kt * 32);
                        cz  = MFMA(wg[0][kt], B, cz);
                        cr  = MFMA(wg[1][kt], B, cr);
                        cxh = MFMA(wg[2][kt], B, cxh);
                    }
                }
                {
                    const _Float16* bs = Hst + bb * SH + quad * 8;
#pragma unroll
                    for (int kt = 0; kt < 4; ++kt) {  // state part (U): h_prev
                        const half8 B = *(const half8*)(bs + kt * 32);
                        cz  = MFMA(wg[0][4 + kt], B, cz);
                        cr  = MFMA(wg[1][4 + kt], B, cr);
                        cuh = MFMA(wg[2][4 + kt], B, cuh);
                    }
                }
                // C/D: col(N)=l15 -> batch bb; row(M)=quad*4+i2 -> d0+quad*4+i2
                const int hoff = bb * SH + d0 + quad * 4;
                const fp16x4 hp4 = *(const fp16x4*)(Hst + hoff);
                fp16x4 hn4;
#pragma unroll
                for (int i2 = 0; i2 < 4; ++i2) {
                    const float z = sigm(cz[i2]);
                    const float r = sigm(cr[i2]);
                    const float hh = cxh[i2] + r * cuh[i2];
                    hn4[i2] = (__fp16)(hh + z * ((float)hp4[i2] - hh));
                }
                *(fp16x4*)(Hout + hoff) = hn4;
            }
        }
        __syncthreads();
    }

    // ---- epilogue: out = h2(T-1) @ Wout; h2 is in H2[0]. Flipped operands:
    // A = Wout^T (regs), B = h2 (LDS). Waves 8-15, 16 out-cols each.
    if (layer) {
        half8 wO[4];
#pragma unroll
        for (int kt = 0; kt < 4; ++kt) {
            half8 f;
#pragma unroll
            for (int e = 0; e < 8; ++e)
                f[e] = (_Float16)Wout[(size_t)(kt * 32 + quad * 8 + e) * D + d0 + l15];
            wO[kt] = f;
        }
#pragma unroll
        for (int nt = 0; nt < 4; ++nt) {
            const _Float16* bp = H2[0] + (nt * 16 + l15) * SH + quad * 8;
            f32x4 acc = {0.f, 0.f, 0.f, 0.f};
#pragma unroll
            for (int kt = 0; kt < 4; ++kt)
                acc = MFMA(wO[kt], *(const half8*)(bp + kt * 32), acc);
            *(f32x4*)(out + (size_t)(b0 + nt * 16 + l15) * D + d0 + quad * 4) = acc;
        }
    }
}

extern "C" void kernel_launch(void* const* d_in, const int* in_sizes, int n_in,
                              void* d_out, int out_size, void* d_ws, size_t ws_size,
                              hipStream_t stream) {
    const float* x    = (const float*)d_in[0];
    const float* W1   = (const float*)d_in[1];
    const float* U1   = (const float*)d_in[2];
    const float* W2   = (const float*)d_in[3];
    const float* U2   = (const float*)d_in[4];
    const float* Wout = (const float*)d_in[5];
    gru2_kernel<<<dim3(16384 / BT), dim3(1024), 0, stream>>>(
        x, W1, U1, W2, U2, Wout, (float*)d_out);
}